// Round 4
// baseline (538.209 us; speedup 1.0000x reference)
//
#include <hip/hip_runtime.h>
#include <hip/hip_bf16.h>

namespace {
constexpr int S = 2048;
constexpr int D = 64;
constexpr int QBLK = 16;   // q-rows per block; p~ cache = 16*2048*2B = 64 KB
constexpr int KBLK = 64;   // k-rows per staged tile
constexpr float QSCALE = 0.18033688011112042f;  // (1/sqrt(64)) * log2(e)

using f32x4 = __attribute__((ext_vector_type(4))) float;
using bf16x8 = __attribute__((ext_vector_type(8))) short;

// dynamic-LDS carve-out (bytes): exactly 80 KiB -> 2 blocks/CU
constexpr int PT_OFF = 0;                      // short[16][2048] XOR-swizzled (64 KB)
constexpr int K_OFF  = QBLK * S * 2;           // short[64][64]   XOR-swizzled (8 KB)
constexpr int V_OFF  = K_OFF + KBLK * D * 2;   // vt[d][j] bf16   XOR-swizzled (8 KB)
constexpr int SMEM_BYTES = V_OFF + KBLK * D * 2;  // 81920 B

__device__ __forceinline__ short f2bf(float f) {
  return __builtin_bit_cast(short, __float2bfloat16(f));
}
__device__ __forceinline__ float bf2f(short s) {
  return __builtin_bit_cast(float, (unsigned)(unsigned short)s << 16);
}
#if __has_builtin(__builtin_amdgcn_exp2f)
__device__ __forceinline__ float exp2_fast(float x) { return __builtin_amdgcn_exp2f(x); }
#else
__device__ __forceinline__ float exp2_fast(float x) { return exp2f(x); }
#endif

__device__ __forceinline__ void bar_lds() {  // lgkm-only barrier: vmem stays in flight
  asm volatile("s_waitcnt lgkmcnt(0)" ::: "memory");
  __builtin_amdgcn_s_barrier();
}
}  // namespace

__global__ __launch_bounds__(256, 2) void attn_fwd(const float* __restrict__ qg,
                                                   const float* __restrict__ kg,
                                                   const float* __restrict__ vg,
                                                   float* __restrict__ outg) {
  extern __shared__ char smem[];
  short* const pt = (short*)(smem + PT_OFF);
  short* const kl = (short*)(smem + K_OFF);
  short* const vt = (short*)(smem + V_OFF);

  const int tid = threadIdx.x;
  const int w = tid >> 6;      // wave: QK j-subtile AND PV d-subtile
  const int lane = tid & 63;
  const int lg = lane >> 4;
  const int lr = lane & 15;

  const int bh = blockIdx.x >> 7;
  const int qt = 127 - (blockIdx.x & 127);  // big blocks first -> short ones fill the tail
  const int qrow0 = qt * QBLK;
  const int ktN = qrow0 >> 6;
  const int NT = ktN + 1;

  const size_t bh_off = (size_t)bh * S * D;
  float* const og = outg;                                                // [64][S][D]
  float* const arow_base = outg + (size_t)64 * S * D + (size_t)bh * S * S;

  const int asw = (lr & 7) << 3;  // row-XOR swizzle (shorts) for all frag accesses

  // ---- Q B-fragment: col i = lr, k = d (QSCALE*log2e folded in) ----
  bf16x8 qf0, qf1;
  {
    const float* qp = qg + bh_off + (size_t)(qrow0 + lr) * D + lg * 8;
    f32x4 x0 = *(const f32x4*)(qp);
    f32x4 x1 = *(const f32x4*)(qp + 4);
    f32x4 y0 = *(const f32x4*)(qp + 32);
    f32x4 y1 = *(const f32x4*)(qp + 36);
#pragma unroll
    for (int e = 0; e < 4; ++e) {
      qf0[e]     = f2bf(x0[e] * QSCALE);
      qf0[e + 4] = f2bf(x1[e] * QSCALE);
      qf1[e]     = f2bf(y0[e] * QSCALE);
      qf1[e + 4] = f2bf(y1[e] * QSCALE);
    }
  }

  // staging maps: K: row=tid>>2 cols (tid&3)*16..+15 ; V: row j=tid&63, d0=(tid>>6)*16
  const int krow = tid >> 2;
  const int kc = (tid & 3) * 16;
  const int vj = tid & 63;
  const int vd0 = (tid >> 6) * 16;

  // prologue: register-load tile 0
  f32x4 ka[4], va[4];
  {
    const float* kp = kg + bh_off + (size_t)krow * D + kc;
#pragma unroll
    for (int i = 0; i < 4; ++i) ka[i] = *(const f32x4*)(kp + i * 4);
    const float* vp = vg + bh_off + (size_t)vj * D + vd0;
#pragma unroll
    for (int i = 0; i < 4; ++i) va[i] = *(const f32x4*)(vp + i * 4);
  }

  float l_acc = 0.f;
  f32x4 oacc = {0.f, 0.f, 0.f, 0.f};
  const int igl = qrow0 + lr;  // this lane's q-row in QK

  for (int kt = 0; kt < NT; ++kt) {
    // ---- stage-write: regs -> LDS bf16 swizzled ----
    {
      bf16x8 kb;
#pragma unroll
      for (int e = 0; e < 4; ++e) { kb[e] = f2bf(ka[0][e]); kb[e + 4] = f2bf(ka[1][e]); }
      *(bf16x8*)(&kl[(krow * 64 + kc) ^ ((krow & 7) << 3)]) = kb;
#pragma unroll
      for (int e = 0; e < 4; ++e) { kb[e] = f2bf(ka[2][e]); kb[e + 4] = f2bf(ka[3][e]); }
      *(bf16x8*)(&kl[(krow * 64 + kc + 8) ^ ((krow & 7) << 3)]) = kb;
#pragma unroll
      for (int i = 0; i < 4; ++i) {
#pragma unroll
        for (int e = 0; e < 4; ++e) {
          const int d = vd0 + i * 4 + e;
          vt[(d * 64 + vj) ^ ((d & 7) << 3)] = f2bf(va[i][e]);  // d uniform/instr
        }
      }
    }
    bar_lds();

    // ---- prefetch next tile into regs (T14: HBM latency hides under QK+PV) ----
    if (kt + 1 < NT) {
      const float* kp = kg + bh_off + (size_t)((kt + 1) * KBLK + krow) * D + kc;
#pragma unroll
      for (int i = 0; i < 4; ++i) ka[i] = *(const f32x4*)(kp + i * 4);
      const float* vp = vg + bh_off + (size_t)((kt + 1) * KBLK + vj) * D + vd0;
#pragma unroll
      for (int i = 0; i < 4; ++i) va[i] = *(const f32x4*)(vp + i * 4);
    }

    // ---- QK^T(kt): wave w -> j-subtile w; D[j][i]: lane col i=lr, rows j=w*16+lg*4+r ----
    {
      const int arow_l = (w * 16 + lr) * 64;
      bf16x8 kf0 = *(const bf16x8*)(&kl[(arow_l + lg * 8) ^ asw]);
      bf16x8 kf1 = *(const bf16x8*)(&kl[(arow_l + 32 + lg * 8) ^ asw]);
      f32x4 sacc = {0.f, 0.f, 0.f, 0.f};
      sacc = __builtin_amdgcn_mfma_f32_16x16x32_bf16(kf0, qf0, sacc, 0, 0, 0);
      sacc = __builtin_amdgcn_mfma_f32_16x16x32_bf16(kf1, qf1, sacc, 0, 0, 0);

      const int jgl_base = kt * 64 + w * 16 + lg * 4;
      float pr[4];
      if (kt == ktN) {
#pragma unroll
        for (int r = 0; r < 4; ++r)
          pr[r] = (jgl_base + r > igl) ? 0.f : exp2_fast(sacc[r]);
      } else {
#pragma unroll
        for (int r = 0; r < 4; ++r) pr[r] = exp2_fast(sacc[r]);
      }
      l_acc += (pr[0] + pr[1]) + (pr[2] + pr[3]);
      short4 ps;
      ps.x = f2bf(pr[0]); ps.y = f2bf(pr[1]); ps.z = f2bf(pr[2]); ps.w = f2bf(pr[3]);
      *(short4*)(&pt[(lr * S + jgl_base) ^ asw]) = ps;
    }
    bar_lds();

    // ---- PV(kt): wave w -> d-subtile w; O[i][d] += p~ V ----
    {
      const int vrow_l = (w * 16 + lr) * 64;
#pragma unroll
      for (int ks = 0; ks < 2; ++ks) {
        bf16x8 pa = *(const bf16x8*)(&pt[(lr * S + kt * 64 + ks * 32 + lg * 8) ^ asw]);
        bf16x8 vb = *(const bf16x8*)(&vt[(vrow_l + ks * 32 + lg * 8) ^ asw]);
        oacc = __builtin_amdgcn_mfma_f32_16x16x32_bf16(pa, vb, oacc, 0, 0, 0);
      }
    }
    bar_lds();  // next stage-write may overwrite kl/vt
  }

  // ---- l-reduction; lp/rlv live in the (dead) K region ----
  float* const lp = (float*)(smem + K_OFF);
  float* const rlv = lp + 64;
  l_acc += __shfl_xor(l_acc, 16, 64);
  l_acc += __shfl_xor(l_acc, 32, 64);
  if (lane < 16) lp[w * 16 + lane] = l_acc;
  bar_lds();
  if (tid < 16) {
    rlv[tid] = 1.f / (lp[tid] + lp[16 + tid] + lp[32 + tid] + lp[48 + tid]);
  }
  bar_lds();

  // ---- O write: lane holds O[i=lg*4+r][d=w*16+lr] ----
#pragma unroll
  for (int r = 0; r < 4; ++r) {
    const int il = lg * 4 + r;
    __builtin_nontemporal_store(oacc[r] * rlv[il],
                                &og[bh_off + (size_t)(qrow0 + il) * D + w * 16 + lr]);
  }

  // ---- normalize-sweep: a[i][j] = bf2f(p~)*rl ; zero-fill beyond diagonal tiles ----
  {
    const int si = tid >> 4;           // 0..15: q-row
    const int c0 = (tid & 15) * 8;     // 8 cols per thread per step
    float* const arow = arow_base + (size_t)(qrow0 + si) * S;
    const float rls = rlv[si];
    const int ssw = (si & 7) << 3;
    const int vcols = NT * 64;
    for (int c = c0; c < S; c += 128) {
      f32x4 o0, o1;
      if (c < vcols) {
        bf16x8 p8 = *(const bf16x8*)(&pt[(si * S + c) ^ ssw]);
        o0[0] = bf2f(p8[0]) * rls; o0[1] = bf2f(p8[1]) * rls;
        o0[2] = bf2f(p8[2]) * rls; o0[3] = bf2f(p8[3]) * rls;
        o1[0] = bf2f(p8[4]) * rls; o1[1] = bf2f(p8[5]) * rls;
        o1[2] = bf2f(p8[6]) * rls; o1[3] = bf2f(p8[7]) * rls;
      } else {
        o0 = (f32x4){0.f, 0.f, 0.f, 0.f};
        o1 = o0;
      }
      __builtin_nontemporal_store(o0, (f32x4*)(arow + c));
      __builtin_nontemporal_store(o1, (f32x4*)(arow + c + 4));
    }
  }
}

extern "C" void kernel_launch(void* const* d_in, const int* in_sizes, int n_in,
                              void* d_out, int out_size, void* d_ws, size_t ws_size,
                              hipStream_t stream) {
  const float* q = (const float*)d_in[0];
  const float* k = (const float*)d_in[1];
  const float* v = (const float*)d_in[2];
  float* out = (float*)d_out;
  (void)hipFuncSetAttribute((const void*)attn_fwd,
                            hipFuncAttributeMaxDynamicSharedMemorySize, SMEM_BYTES);
  attn_fwd<<<dim3(64 * 128), dim3(256), SMEM_BYTES, stream>>>(q, k, v, out);
}

// Round 5
// 466.333 us; speedup vs baseline: 1.1541x; 1.1541x over previous
//
#include <hip/hip_runtime.h>
#include <hip/hip_bf16.h>

namespace {
constexpr int S = 2048;
constexpr int D = 64;
constexpr float QSCALE = 0.18033688011112042f;  // (1/sqrt(64)) * log2(e)

using f32x4 = __attribute__((ext_vector_type(4))) float;
using bf16x8 = __attribute__((ext_vector_type(8))) short;

__device__ __forceinline__ short f2bf(float f) {
  return __builtin_bit_cast(short, __float2bfloat16(f));  // native RNE cvt
}
#if __has_builtin(__builtin_amdgcn_exp2f)
__device__ __forceinline__ float exp2_fast(float x) { return __builtin_amdgcn_exp2f(x); }
#else
__device__ __forceinline__ float exp2_fast(float x) { return exp2f(x); }
#endif

__device__ __forceinline__ void bar_lds() {  // lgkm-only barrier: vmem prefetch stays in flight
  asm volatile("s_waitcnt lgkmcnt(0)" ::: "memory");
  __builtin_amdgcn_s_barrier();
}
}  // namespace

// ============ kernel 1: row expsums l -> stash rl=1/l into o[bh][i][0] ============
// QBLK=128 rows/block, 4 waves; wave w owns i-rows w*32..w*32+31 (2 sub-tiles of 16).
__global__ __launch_bounds__(256, 4) void l_pass(const float* __restrict__ qg,
                                                 const float* __restrict__ kg,
                                                 float* __restrict__ outg) {
  __shared__ short kbuf[2][64 * 64];  // K tile bf16, XOR-swizzled, double-buffered

  const int tid = threadIdx.x;
  const int w = tid >> 6, lane = tid & 63, lg = lane >> 4, lr = lane & 15;
  const int b = blockIdx.x;
  const int logical = (b & 7) * 128 + (b >> 3);  // XCD-contiguous chunks (1024 % 8 == 0)
  const int bh = logical >> 4;
  const int qt2 = logical & 15;
  const int qrow0 = qt2 * 128;
  const int NT = 2 * qt2 + 2;
  const size_t bh_off = (size_t)bh * S * D;
  const int asw = (lr & 7) << 3;

  // Q B-fragments: col i = qrow0 + w*32 + ib*16 + lr, k = kh*32 + lg*8 + e
  bf16x8 qf[2][2];
#pragma unroll
  for (int ib = 0; ib < 2; ++ib) {
#pragma unroll
    for (int kh = 0; kh < 2; ++kh) {
      const float* qp = qg + bh_off + (size_t)(qrow0 + w * 32 + ib * 16 + lr) * D + kh * 32 + lg * 8;
      f32x4 x0 = *(const f32x4*)(qp);
      f32x4 x1 = *(const f32x4*)(qp + 4);
      bf16x8 f;
#pragma unroll
      for (int e = 0; e < 4; ++e) {
        f[e] = f2bf(x0[e] * QSCALE);
        f[e + 4] = f2bf(x1[e] * QSCALE);
      }
      qf[ib][kh] = f;
    }
  }

  const int krow = tid >> 2, kc = (tid & 3) * 16;
  const int kswz = (krow & 7) << 3;

  f32x4 ka[4];
  {
    const float* kp = kg + bh_off + (size_t)krow * D + kc;
#pragma unroll
    for (int i = 0; i < 4; ++i) ka[i] = *(const f32x4*)(kp + i * 4);
  }
  {  // stage tile 0 -> kbuf[0]
    bf16x8 kb;
#pragma unroll
    for (int e = 0; e < 4; ++e) { kb[e] = f2bf(ka[0][e]); kb[e + 4] = f2bf(ka[1][e]); }
    *(bf16x8*)(&kbuf[0][(krow * 64 + kc) ^ kswz]) = kb;
#pragma unroll
    for (int e = 0; e < 4; ++e) { kb[e] = f2bf(ka[2][e]); kb[e + 4] = f2bf(ka[3][e]); }
    *(bf16x8*)(&kbuf[0][(krow * 64 + kc + 8) ^ kswz]) = kb;
  }
  bar_lds();

  float l0 = 0.f, l1 = 0.f;

  for (int kt = 0; kt < NT; ++kt) {
    const int cur = kt & 1;
    if (kt + 1 < NT) {  // prefetch next K tile into regs (overlaps compute below)
      const float* kp = kg + bh_off + (size_t)((kt + 1) * 64 + krow) * D + kc;
#pragma unroll
      for (int i = 0; i < 4; ++i) ka[i] = *(const f32x4*)(kp + i * 4);
    }

    f32x4 acc[2][4];
#pragma unroll
    for (int ib = 0; ib < 2; ++ib)
#pragma unroll
      for (int jb = 0; jb < 4; ++jb) acc[ib][jb] = (f32x4){0.f, 0.f, 0.f, 0.f};

    __builtin_amdgcn_s_setprio(1);
#pragma unroll
    for (int kh = 0; kh < 2; ++kh) {
#pragma unroll
      for (int jb = 0; jb < 4; ++jb) {
        bf16x8 kf = *(const bf16x8*)(&kbuf[cur][((jb * 16 + lr) * 64 + kh * 32 + lg * 8) ^ asw]);
        acc[0][jb] = __builtin_amdgcn_mfma_f32_16x16x32_bf16(kf, qf[0][kh], acc[0][jb], 0, 0, 0);
        acc[1][jb] = __builtin_amdgcn_mfma_f32_16x16x32_bf16(kf, qf[1][kh], acc[1][jb], 0, 0, 0);
      }
    }
    __builtin_amdgcn_s_setprio(0);

    const bool mask = (kt >= NT - 2);
#pragma unroll
    for (int ib = 0; ib < 2; ++ib) {
      const int igl = qrow0 + w * 32 + ib * 16 + lr;
      float part = 0.f;
#pragma unroll
      for (int jb = 0; jb < 4; ++jb) {
#pragma unroll
        for (int r = 0; r < 4; ++r) {
          const int jgl = kt * 64 + jb * 16 + lg * 4 + r;
          float e = exp2_fast(acc[ib][jb][r]);
          if (mask && jgl > igl) e = 0.f;
          part += e;
        }
      }
      if (ib == 0) l0 += part; else l1 += part;
    }

    if (kt + 1 < NT) {  // stage next tile into the other buffer
      bf16x8 kb;
#pragma unroll
      for (int e = 0; e < 4; ++e) { kb[e] = f2bf(ka[0][e]); kb[e + 4] = f2bf(ka[1][e]); }
      *(bf16x8*)(&kbuf[cur ^ 1][(krow * 64 + kc) ^ kswz]) = kb;
#pragma unroll
      for (int e = 0; e < 4; ++e) { kb[e] = f2bf(ka[2][e]); kb[e + 4] = f2bf(ka[3][e]); }
      *(bf16x8*)(&kbuf[cur ^ 1][(krow * 64 + kc + 8) ^ kswz]) = kb;
    }
    bar_lds();
  }

  // reduce over lg groups (j coverage) and stash rl into o[bh][i][0]
  l0 += __shfl_xor(l0, 16, 64);
  l0 += __shfl_xor(l0, 32, 64);
  l1 += __shfl_xor(l1, 16, 64);
  l1 += __shfl_xor(l1, 32, 64);
  if (lane < 16) {
    outg[bh_off + (size_t)(qrow0 + w * 32 + lane) * D] = 1.f / l0;
    outg[bh_off + (size_t)(qrow0 + w * 32 + 16 + lane) * D] = 1.f / l1;
  }
}

// ============ kernel 2: emit a (normalized, streamed) + O ============
// QBLK=64 rows/block, 4 waves; wave w owns i-rows w*16..w*16+15. 40 KB LDS -> 4 blocks/CU.
__global__ __launch_bounds__(256, 4) void emit_pass(const float* __restrict__ qg,
                                                    const float* __restrict__ kg,
                                                    const float* __restrict__ vg,
                                                    float* __restrict__ outg) {
  __shared__ short kbuf[2][64 * 64];   // K[j][d] bf16 swizzled (dbuf)
  __shared__ short vbuf[2][64 * 64];   // V^T[d][j] bf16 swizzled (dbuf)
  __shared__ short pscr[4][16 * 64];   // per-wave p~ redistribution scratch

  const int tid = threadIdx.x;
  const int w = tid >> 6, lane = tid & 63, lg = lane >> 4, lr = lane & 15;
  const int b = blockIdx.x;
  const int logical = (b & 7) * 256 + (b >> 3);  // XCD-contiguous chunks (2048 % 8 == 0)
  const int bh = logical >> 5;
  const int qt = logical & 31;
  const int qrow0 = qt * 64;
  const int NT = qt + 1;
  const size_t bh_off = (size_t)bh * S * D;
  float* const og = outg;
  float* const a_base = outg + (size_t)64 * S * D + (size_t)bh * S * S;
  const int asw = (lr & 7) << 3;

  const int igl = qrow0 + w * 16 + lr;  // this lane's q-row (QK col / p row)

  // rl from kernel-1 stash (read BEFORE this block overwrites o)
  const float rlA = og[bh_off + (size_t)igl * D];
  float rlO[4];
#pragma unroll
  for (int r = 0; r < 4; ++r)
    rlO[r] = og[bh_off + (size_t)(qrow0 + w * 16 + lg * 4 + r) * D];

  // Q B-fragment
  bf16x8 qf[2];
#pragma unroll
  for (int kh = 0; kh < 2; ++kh) {
    const float* qp = qg + bh_off + (size_t)igl * D + kh * 32 + lg * 8;
    f32x4 x0 = *(const f32x4*)(qp);
    f32x4 x1 = *(const f32x4*)(qp + 4);
    bf16x8 f;
#pragma unroll
    for (int e = 0; e < 4; ++e) {
      f[e] = f2bf(x0[e] * QSCALE);
      f[e + 4] = f2bf(x1[e] * QSCALE);
    }
    qf[kh] = f;
  }

  const int krow = tid >> 2, kc = (tid & 3) * 16;
  const int kswz = (krow & 7) << 3;
  const int vj = tid & 63, vd0 = (tid >> 6) * 16;

  f32x4 ka[4], va[4];
  {
    const float* kp = kg + bh_off + (size_t)krow * D + kc;
#pragma unroll
    for (int i = 0; i < 4; ++i) ka[i] = *(const f32x4*)(kp + i * 4);
    const float* vp = vg + bh_off + (size_t)vj * D + vd0;
#pragma unroll
    for (int i = 0; i < 4; ++i) va[i] = *(const f32x4*)(vp + i * 4);
  }
  {  // stage tile 0
    bf16x8 kb;
#pragma unroll
    for (int e = 0; e < 4; ++e) { kb[e] = f2bf(ka[0][e]); kb[e + 4] = f2bf(ka[1][e]); }
    *(bf16x8*)(&kbuf[0][(krow * 64 + kc) ^ kswz]) = kb;
#pragma unroll
    for (int e = 0; e < 4; ++e) { kb[e] = f2bf(ka[2][e]); kb[e + 4] = f2bf(ka[3][e]); }
    *(bf16x8*)(&kbuf[0][(krow * 64 + kc + 8) ^ kswz]) = kb;
#pragma unroll
    for (int i = 0; i < 4; ++i)
#pragma unroll
      for (int e = 0; e < 4; ++e) {
        const int d = vd0 + i * 4 + e;
        vbuf[0][(d * 64 + vj) ^ ((d & 7) << 3)] = f2bf(va[i][e]);
      }
  }
  bar_lds();

  f32x4 oacc[4];
#pragma unroll
  for (int dg = 0; dg < 4; ++dg) oacc[dg] = (f32x4){0.f, 0.f, 0.f, 0.f};

  float* const arow = a_base + (size_t)igl * S;

  for (int kt = 0; kt < NT; ++kt) {
    const int cur = kt & 1;
    if (kt + 1 < NT) {  // prefetch next K/V tiles into regs
      const float* kp = kg + bh_off + (size_t)((kt + 1) * 64 + krow) * D + kc;
#pragma unroll
      for (int i = 0; i < 4; ++i) ka[i] = *(const f32x4*)(kp + i * 4);
      const float* vp = vg + bh_off + (size_t)((kt + 1) * 64 + vj) * D + vd0;
#pragma unroll
      for (int i = 0; i < 4; ++i) va[i] = *(const f32x4*)(vp + i * 4);
    }

    // ---- QK^T: D[j][i], lane col i = lr, rows j = jb*16 + lg*4 + r ----
    f32x4 sacc[4];
#pragma unroll
    for (int jb = 0; jb < 4; ++jb) sacc[jb] = (f32x4){0.f, 0.f, 0.f, 0.f};
    __builtin_amdgcn_s_setprio(1);
#pragma unroll
    for (int kh = 0; kh < 2; ++kh) {
#pragma unroll
      for (int jb = 0; jb < 4; ++jb) {
        bf16x8 kf = *(const bf16x8*)(&kbuf[cur][((jb * 16 + lr) * 64 + kh * 32 + lg * 8) ^ asw]);
        sacc[jb] = __builtin_amdgcn_mfma_f32_16x16x32_bf16(kf, qf[kh], sacc[jb], 0, 0, 0);
      }
    }
    __builtin_amdgcn_s_setprio(0);

    // ---- p~ = exp2(s); a-store normalized (fp32, streamed); pscr for PV ----
    const bool diag = (kt == NT - 1);
#pragma unroll
    for (int jb = 0; jb < 4; ++jb) {
      f32x4 av;
      short4 ps;
#pragma unroll
      for (int r = 0; r < 4; ++r) {
        const int jgl = kt * 64 + jb * 16 + lg * 4 + r;
        float pt = exp2_fast(sacc[jb][r]);
        if (diag && jgl > igl) pt = 0.f;
        av[r] = pt * rlA;
        ((short*)&ps)[r] = f2bf(pt);
      }
      __builtin_nontemporal_store(av, (f32x4*)(arow + kt * 64 + jb * 16 + lg * 4));
      *(short4*)(&pscr[w][(lr * 64 + jb * 16 + lg * 4) ^ asw]) = ps;
    }

    // ---- PV: O[i][d] += p~ V  (pscr same-wave, LDS is in-order per wave) ----
    __builtin_amdgcn_s_setprio(1);
#pragma unroll
    for (int ks = 0; ks < 2; ++ks) {
      bf16x8 pa = *(const bf16x8*)(&pscr[w][(lr * 64 + ks * 32 + lg * 8) ^ asw]);
#pragma unroll
      for (int dg = 0; dg < 4; ++dg) {
        bf16x8 vb = *(const bf16x8*)(&vbuf[cur][((dg * 16 + lr) * 64 + ks * 32 + lg * 8) ^ asw]);
        oacc[dg] = __builtin_amdgcn_mfma_f32_16x16x32_bf16(pa, vb, oacc[dg], 0, 0, 0);
      }
    }
    __builtin_amdgcn_s_setprio(0);

    if (kt + 1 < NT) {  // stage next tile into the other buffers
      bf16x8 kb;
#pragma unroll
      for (int e = 0; e < 4; ++e) { kb[e] = f2bf(ka[0][e]); kb[e + 4] = f2bf(ka[1][e]); }
      *(bf16x8*)(&kbuf[cur ^ 1][(krow * 64 + kc) ^ kswz]) = kb;
#pragma unroll
      for (int e = 0; e < 4; ++e) { kb[e] = f2bf(ka[2][e]); kb[e + 4] = f2bf(ka[3][e]); }
      *(bf16x8*)(&kbuf[cur ^ 1][(krow * 64 + kc + 8) ^ kswz]) = kb;
#pragma unroll
      for (int i = 0; i < 4; ++i)
#pragma unroll
        for (int e = 0; e < 4; ++e) {
          const int d = vd0 + i * 4 + e;
          vbuf[cur ^ 1][(d * 64 + vj) ^ ((d & 7) << 3)] = f2bf(va[i][e]);
        }
    }
    bar_lds();
  }

  // ---- O write (overwrites the rl stash; rlO already in regs) ----
#pragma unroll
  for (int dg = 0; dg < 4; ++dg) {
#pragma unroll
    for (int r = 0; r < 4; ++r) {
      const int il = qrow0 + w * 16 + lg * 4 + r;
      __builtin_nontemporal_store(oacc[dg][r] * rlO[r],
                                  &og[bh_off + (size_t)il * D + dg * 16 + lr]);
    }
  }

  // ---- tail zero-fill: a[i][j] = 0 for j >= NT*64 ----
  const int zc0 = NT * 64;
  if (zc0 < S) {
    const int row = tid >> 2;
    float* ar = a_base + (size_t)(qrow0 + row) * S;
    const f32x4 z = {0.f, 0.f, 0.f, 0.f};
    for (int c = zc0 + (tid & 3) * 4; c < S; c += 16) {
      __builtin_nontemporal_store(z, (f32x4*)(ar + c));
    }
  }
}

extern "C" void kernel_launch(void* const* d_in, const int* in_sizes, int n_in,
                              void* d_out, int out_size, void* d_ws, size_t ws_size,
                              hipStream_t stream) {
  const float* q = (const float*)d_in[0];
  const float* k = (const float*)d_in[1];
  const float* v = (const float*)d_in[2];
  float* out = (float*)d_out;
  l_pass<<<dim3(1024), dim3(256), 0, stream>>>(q, k, out);
  emit_pass<<<dim3(2048), dim3(256), 0, stream>>>(q, k, v, out);
}

// Round 6
// 370.935 us; speedup vs baseline: 1.4510x; 1.2572x over previous
//
#include <hip/hip_runtime.h>
#include <hip/hip_bf16.h>

namespace {
constexpr int S = 2048;
constexpr int D = 64;
constexpr float QSCALE = 0.18033688011112042f;  // (1/sqrt(64)) * log2(e)

using f32x4 = __attribute__((ext_vector_type(4))) float;
using bf16x8 = __attribute__((ext_vector_type(8))) short;

__device__ __forceinline__ short f2bf(float f) {
  return __builtin_bit_cast(short, __float2bfloat16(f));  // native RNE cvt
}
#if __has_builtin(__builtin_amdgcn_exp2f)
__device__ __forceinline__ float exp2_fast(float x) { return __builtin_amdgcn_exp2f(x); }
#else
__device__ __forceinline__ float exp2_fast(float x) { return exp2f(x); }
#endif

__device__ __forceinline__ void bar_lds() {  // lgkm-only barrier: vmem prefetch stays in flight
  asm volatile("s_waitcnt lgkmcnt(0)" ::: "memory");
  __builtin_amdgcn_s_barrier();
}
}  // namespace

// One block = (bh, 64 q-rows). Loop A: QK+exp-sum+PV (no stores). Loop B: QK
// recompute -> normalized a streamed out (incl. zero tiles). 40KB LDS -> 4 blocks/CU.
__global__ __launch_bounds__(256, 4) void attn_fused(const float* __restrict__ qg,
                                                     const float* __restrict__ kg,
                                                     const float* __restrict__ vg,
                                                     float* __restrict__ outg) {
  __shared__ short kbuf[2][64 * 64];   // K[j][d] bf16, XOR-swizzled, dbuf
  __shared__ short vbuf[2][64 * 64];   // V^T[d][j] bf16, XOR-swizzled, dbuf
  __shared__ short pscr[4][16 * 64];   // per-wave p~ redistribution scratch

  const int tid = threadIdx.x;
  const int w = tid >> 6, lane = tid & 63, lg = lane >> 4, lr = lane & 15;

  // XCD-chunked block map + long/short qt interleave for co-resident balance
  const int u = blockIdx.x;
  const int logical = (u & 7) * 256 + (u >> 3);  // 2048 % 8 == 0
  const int bh = logical >> 5;
  const int uu = logical & 31;
  const int qt = (uu & 1) ? (31 - (uu >> 1)) : (uu >> 1);
  const int qrow0 = qt * 64;
  const int NT = qt + 1;

  const size_t bh_off = (size_t)bh * S * D;
  float* const og = outg;
  float* const a_base = outg + (size_t)64 * S * D + (size_t)bh * S * S;
  const int asw = (lr & 7) << 3;

  const int igl = qrow0 + w * 16 + lr;  // this lane's q-row (QK col i / p row)

  // ---- Q B-fragment (col i = lr-row of this wave, k = d), QSCALE folded ----
  bf16x8 qf[2];
#pragma unroll
  for (int kh = 0; kh < 2; ++kh) {
    const float* qp = qg + bh_off + (size_t)igl * D + kh * 32 + lg * 8;
    f32x4 x0 = *(const f32x4*)(qp);
    f32x4 x1 = *(const f32x4*)(qp + 4);
    bf16x8 f;
#pragma unroll
    for (int e = 0; e < 4; ++e) {
      f[e] = f2bf(x0[e] * QSCALE);
      f[e + 4] = f2bf(x1[e] * QSCALE);
    }
    qf[kh] = f;
  }

  const int krow = tid >> 2, kc = (tid & 3) * 16;
  const int kswz = (krow & 7) << 3;
  const int vj = tid & 63, vd0 = (tid >> 6) * 16;

  // =========================== loop A: l + O(unnormalized) ===========================
  f32x4 ka[4], va[4];
  {
    const float* kp = kg + bh_off + (size_t)krow * D + kc;
#pragma unroll
    for (int i = 0; i < 4; ++i) ka[i] = *(const f32x4*)(kp + i * 4);
    const float* vp = vg + bh_off + (size_t)vj * D + vd0;
#pragma unroll
    for (int i = 0; i < 4; ++i) va[i] = *(const f32x4*)(vp + i * 4);
  }
  {  // stage tile 0
    bf16x8 kb;
#pragma unroll
    for (int e = 0; e < 4; ++e) { kb[e] = f2bf(ka[0][e]); kb[e + 4] = f2bf(ka[1][e]); }
    *(bf16x8*)(&kbuf[0][(krow * 64 + kc) ^ kswz]) = kb;
#pragma unroll
    for (int e = 0; e < 4; ++e) { kb[e] = f2bf(ka[2][e]); kb[e + 4] = f2bf(ka[3][e]); }
    *(bf16x8*)(&kbuf[0][(krow * 64 + kc + 8) ^ kswz]) = kb;
#pragma unroll
    for (int i = 0; i < 4; ++i)
#pragma unroll
      for (int e = 0; e < 4; ++e) {
        const int d = vd0 + i * 4 + e;
        vbuf[0][(d * 64 + vj) ^ ((d & 7) << 3)] = f2bf(va[i][e]);
      }
  }
  bar_lds();

  float l_acc = 0.f;
  f32x4 oacc[4];
#pragma unroll
  for (int dg = 0; dg < 4; ++dg) oacc[dg] = (f32x4){0.f, 0.f, 0.f, 0.f};

  for (int kt = 0; kt < NT; ++kt) {
    const int cur = kt & 1;
    if (kt + 1 < NT) {  // prefetch next K/V tiles into regs
      const float* kp = kg + bh_off + (size_t)((kt + 1) * 64 + krow) * D + kc;
#pragma unroll
      for (int i = 0; i < 4; ++i) ka[i] = *(const f32x4*)(kp + i * 4);
      const float* vp = vg + bh_off + (size_t)((kt + 1) * 64 + vj) * D + vd0;
#pragma unroll
      for (int i = 0; i < 4; ++i) va[i] = *(const f32x4*)(vp + i * 4);
    }

    // QK^T: D[j][i], lane col i = lr, rows j = jb*16 + lg*4 + r
    f32x4 sacc[4];
#pragma unroll
    for (int jb = 0; jb < 4; ++jb) sacc[jb] = (f32x4){0.f, 0.f, 0.f, 0.f};
    __builtin_amdgcn_s_setprio(1);
#pragma unroll
    for (int kh = 0; kh < 2; ++kh) {
#pragma unroll
      for (int jb = 0; jb < 4; ++jb) {
        bf16x8 kf = *(const bf16x8*)(&kbuf[cur][((jb * 16 + lr) * 64 + kh * 32 + lg * 8) ^ asw]);
        sacc[jb] = __builtin_amdgcn_mfma_f32_16x16x32_bf16(kf, qf[kh], sacc[jb], 0, 0, 0);
      }
    }
    __builtin_amdgcn_s_setprio(0);

    // p~ = exp2(s) (masked on diagonal tile); accumulate l; pscr for PV
    const bool diag = (kt == NT - 1);
#pragma unroll
    for (int jb = 0; jb < 4; ++jb) {
      short4 ps;
#pragma unroll
      for (int r = 0; r < 4; ++r) {
        const int jgl = kt * 64 + jb * 16 + lg * 4 + r;
        float pt = exp2_fast(sacc[jb][r]);
        if (diag && jgl > igl) pt = 0.f;
        l_acc += pt;
        ((short*)&ps)[r] = f2bf(pt);
      }
      *(short4*)(&pscr[w][(lr * 64 + jb * 16 + lg * 4) ^ asw]) = ps;
    }

    // PV: O[i][d] += p~ V (pscr same-wave)
    __builtin_amdgcn_s_setprio(1);
#pragma unroll
    for (int ks = 0; ks < 2; ++ks) {
      bf16x8 pa = *(const bf16x8*)(&pscr[w][(lr * 64 + ks * 32 + lg * 8) ^ asw]);
#pragma unroll
      for (int dg = 0; dg < 4; ++dg) {
        bf16x8 vb = *(const bf16x8*)(&vbuf[cur][((dg * 16 + lr) * 64 + ks * 32 + lg * 8) ^ asw]);
        oacc[dg] = __builtin_amdgcn_mfma_f32_16x16x32_bf16(pa, vb, oacc[dg], 0, 0, 0);
      }
    }
    __builtin_amdgcn_s_setprio(0);

    if (kt + 1 < NT) {  // stage next tile into the other buffers
      bf16x8 kb;
#pragma unroll
      for (int e = 0; e < 4; ++e) { kb[e] = f2bf(ka[0][e]); kb[e + 4] = f2bf(ka[1][e]); }
      *(bf16x8*)(&kbuf[cur ^ 1][(krow * 64 + kc) ^ kswz]) = kb;
#pragma unroll
      for (int e = 0; e < 4; ++e) { kb[e] = f2bf(ka[2][e]); kb[e + 4] = f2bf(ka[3][e]); }
      *(bf16x8*)(&kbuf[cur ^ 1][(krow * 64 + kc + 8) ^ kswz]) = kb;
#pragma unroll
      for (int i = 0; i < 4; ++i)
#pragma unroll
        for (int e = 0; e < 4; ++e) {
          const int d = vd0 + i * 4 + e;
          vbuf[cur ^ 1][(d * 64 + vj) ^ ((d & 7) << 3)] = f2bf(va[i][e]);
        }
    }
    bar_lds();
  }

  // ---- rl: lane's l_acc is a partial over its lg j-coverage; reduce across lg ----
  l_acc += __shfl_xor(l_acc, 16, 64);
  l_acc += __shfl_xor(l_acc, 32, 64);
  const float rlA = 1.f / l_acc;  // rl for row igl (lane-resident; B uses directly)

  // O rescale needs rl at rows w*16+lg*4+r: bounce via per-wave pscr region
  {
    float* const rlv = (float*)(&pscr[w][0]);
    if (lane < 16) rlv[lr] = rlA;
    asm volatile("s_waitcnt lgkmcnt(0)" ::: "memory");  // same-wave write->read
#pragma unroll
    for (int dg = 0; dg < 4; ++dg) {
#pragma unroll
      for (int r = 0; r < 4; ++r) {
        const int il = qrow0 + w * 16 + lg * 4 + r;
        __builtin_nontemporal_store(oacc[dg][r] * rlv[lg * 4 + r],
                                    &og[bh_off + (size_t)il * D + dg * 16 + lr]);
      }
    }
  }

  // =========================== loop B: stream normalized a ===========================
  float* const arow = a_base + (size_t)igl * S;
  {
    const float* kp = kg + bh_off + (size_t)krow * D + kc;
#pragma unroll
    for (int i = 0; i < 4; ++i) ka[i] = *(const f32x4*)(kp + i * 4);
  }
  {  // stage tile 0 (A-loop reads of kbuf[0] finished at A's last barrier)
    bf16x8 kb;
#pragma unroll
    for (int e = 0; e < 4; ++e) { kb[e] = f2bf(ka[0][e]); kb[e + 4] = f2bf(ka[1][e]); }
    *(bf16x8*)(&kbuf[0][(krow * 64 + kc) ^ kswz]) = kb;
#pragma unroll
    for (int e = 0; e < 4; ++e) { kb[e] = f2bf(ka[2][e]); kb[e + 4] = f2bf(ka[3][e]); }
    *(bf16x8*)(&kbuf[0][(krow * 64 + kc + 8) ^ kswz]) = kb;
  }
  bar_lds();

  for (int kt = 0; kt < NT; ++kt) {
    const int cur = kt & 1;
    if (kt + 1 < NT) {  // prefetch next K tile (issued BEFORE this tile's stores)
      const float* kp = kg + bh_off + (size_t)((kt + 1) * 64 + krow) * D + kc;
#pragma unroll
      for (int i = 0; i < 4; ++i) ka[i] = *(const f32x4*)(kp + i * 4);
    }

    f32x4 sacc[4];
#pragma unroll
    for (int jb = 0; jb < 4; ++jb) sacc[jb] = (f32x4){0.f, 0.f, 0.f, 0.f};
    __builtin_amdgcn_s_setprio(1);
#pragma unroll
    for (int kh = 0; kh < 2; ++kh) {
#pragma unroll
      for (int jb = 0; jb < 4; ++jb) {
        bf16x8 kf = *(const bf16x8*)(&kbuf[cur][((jb * 16 + lr) * 64 + kh * 32 + lg * 8) ^ asw]);
        sacc[jb] = __builtin_amdgcn_mfma_f32_16x16x32_bf16(kf, qf[kh], sacc[jb], 0, 0, 0);
      }
    }
    __builtin_amdgcn_s_setprio(0);

    const bool diag = (kt == NT - 1);
#pragma unroll
    for (int jb = 0; jb < 4; ++jb) {
      f32x4 av;
#pragma unroll
      for (int r = 0; r < 4; ++r) {
        const int jgl = kt * 64 + jb * 16 + lg * 4 + r;
        float pt = exp2_fast(sacc[jb][r]);
        if (diag && jgl > igl) pt = 0.f;
        av[r] = pt * rlA;
      }
      __builtin_nontemporal_store(av, (f32x4*)(arow + kt * 64 + jb * 16 + lg * 4));
    }

    if (kt + 1 < NT) {
      bf16x8 kb;
#pragma unroll
      for (int e = 0; e < 4; ++e) { kb[e] = f2bf(ka[0][e]); kb[e + 4] = f2bf(ka[1][e]); }
      *(bf16x8*)(&kbuf[cur ^ 1][(krow * 64 + kc) ^ kswz]) = kb;
#pragma unroll
      for (int e = 0; e < 4; ++e) { kb[e] = f2bf(ka[2][e]); kb[e + 4] = f2bf(ka[3][e]); }
      *(bf16x8*)(&kbuf[cur ^ 1][(krow * 64 + kc + 8) ^ kswz]) = kb;
    }
    bar_lds();
  }

  // ---- zero tiles (j >= NT*64): pure store stream, no syncs ----
  const f32x4 z = {0.f, 0.f, 0.f, 0.f};
  for (int zt = NT; zt < S / 64; ++zt) {
#pragma unroll
    for (int jb = 0; jb < 4; ++jb) {
      __builtin_nontemporal_store(z, (f32x4*)(arow + zt * 64 + jb * 16 + lg * 4));
    }
  }
}

extern "C" void kernel_launch(void* const* d_in, const int* in_sizes, int n_in,
                              void* d_out, int out_size, void* d_ws, size_t ws_size,
                              hipStream_t stream) {
  const float* q = (const float*)d_in[0];
  const float* k = (const float*)d_in[1];
  const float* v = (const float*)d_in[2];
  float* out = (float*)d_out;
  attn_fused<<<dim3(2048), dim3(256), 0, stream>>>(q, k, v, out);
}